// Round 15
// baseline (89.313 us; speedup 1.0000x reference)
//
#include <hip/hip_runtime.h>
#include <stdint.h>

#define NB 16384      // batch
#define NK 64         // neighbors per node
#define NF 128        // feature dim
#define NS 16         // samples per row
#define RPB 4         // rows (waves) per block

// ---------------------------------------------------------------------------
// Bit-exact replicas of XLA:CPU's float32 exp/log (Cephes-derived polynomials
// from llvm_ir_runtime.cc GenerateVF32Exp/GenerateVF32Log; fmuladd -> FMA).
// DO NOT TOUCH: verified absmax == 0 vs JAX reference in R1/R4/R6-R13.
// ---------------------------------------------------------------------------
__device__ __forceinline__ float xla_exp_f32(float x_in) {
#pragma clang fp contract(off)
  const float exp_hi = 88.3762626647950f;
  const float exp_lo = -88.3762626647949f;
  const float log2ef = 1.44269504088896341f;
  const float c1 = 0.693359375f;
  const float c2 = -2.12194440e-4f;
  const float p0 = 1.9875691500E-4f;
  const float p1 = 1.3981999507E-3f;
  const float p2 = 8.3334519073E-3f;
  const float p3 = 4.1665795894E-2f;
  const float p4 = 1.6666665459E-1f;
  const float p5 = 5.0000001201E-1f;

  float x = fminf(fmaxf(x_in, exp_lo), exp_hi);
  float fx = floorf(fmaf(x, log2ef, 0.5f));
  float tmp = c1 * fx;
  float z2 = c2 * fx;
  x = x - tmp;
  x = x - z2;
  float z = x * x;
  float y = fmaf(x, p0, p1);
  y = fmaf(y, x, p2);
  y = fmaf(y, x, p3);
  y = fmaf(y, x, p4);
  y = fmaf(y, x, p5);
  y = fmaf(y, z, x);
  y = y + 1.0f;
  int n = (int)fx;
  float two_n = __int_as_float((n + 127) << 23);
  return fmaxf(y * two_n, x_in);
}

__device__ __forceinline__ float xla_log_f32(float x_in) {
#pragma clang fp contract(off)
  const float sqrthf = 0.707106781186547524f;
  const float p0 = 7.0376836292E-2f;
  const float p1 = -1.1514610310E-1f;
  const float p2 = 1.1676998740E-1f;
  const float p3 = -1.2420140846E-1f;
  const float p4 = 1.4249322787E-1f;
  const float p5 = -1.6668057665E-1f;
  const float p6 = 2.0000714765E-1f;
  const float p7 = -2.4999993993E-1f;
  const float p8 = 3.3333331174E-1f;
  const float q1 = -2.12194440e-4f;
  const float q2 = 0.693359375f;

  float t = fmaxf(x_in, __uint_as_float(0x00800000u));
  uint32_t bits = __float_as_uint(t);
  float e = (float)((int)(bits >> 23) - 0x7f) + 1.0f;
  float m = __uint_as_float((bits & 0x007fffffu) | 0x3f000000u);
  bool lt = (m < sqrthf);
  float madd = lt ? m : 0.0f;
  e = e - (lt ? 1.0f : 0.0f);
  m = (m + madd) - 1.0f;

  float z = m * m;
  float y = fmaf(m, p0, p1);
  y = fmaf(y, m, p2);
  y = fmaf(y, m, p3);
  y = fmaf(y, m, p4);
  y = fmaf(y, m, p5);
  y = fmaf(y, m, p6);
  y = fmaf(y, m, p7);
  y = fmaf(y, m, p8);
  y = y * m;
  y = y * z;
  y = fmaf(e, q1, y);
  y = y - 0.5f * z;
  float r = m + y;
  r = fmaf(e, q2, r);
  return r;
}

// ---------------------------------------------------------------------------
// Threefry-2x32 with key (0, 42) == jax.random.key(42).
// ---------------------------------------------------------------------------
__device__ __forceinline__ void threefry2x32_k42(uint32_t c0, uint32_t c1,
                                                 uint32_t& o0, uint32_t& o1) {
  const uint32_t k0 = 0u, k1 = 42u;
  const uint32_t k2 = k0 ^ k1 ^ 0x1BD11BDAu;
  uint32_t x0 = c0 + k0, x1 = c1 + k1;
#define TF_R(r) { x0 += x1; x1 = (x1 << (r)) | (x1 >> (32 - (r))); x1 ^= x0; }
  TF_R(13) TF_R(15) TF_R(26) TF_R(6)
  x0 += k1; x1 += k2 + 1u;
  TF_R(17) TF_R(29) TF_R(16) TF_R(24)
  x0 += k2; x1 += k0 + 2u;
  TF_R(13) TF_R(15) TF_R(26) TF_R(6)
  x0 += k0; x1 += k1 + 3u;
  TF_R(17) TF_R(29) TF_R(16) TF_R(24)
  x0 += k1; x1 += k2 + 4u;
  TF_R(13) TF_R(15) TF_R(26) TF_R(6)
  x0 += k2; x1 += k0 + 5u;
#undef TF_R
  o0 = x0; o1 = x1;
}

// jax partitionable threefry, 32-bit path: bits[m] = out0 ^ out1, m < 2^24.
__device__ __forceinline__ uint32_t jax_random_bits32(uint32_t m) {
  uint32_t a, b;
  threefry2x32_k42(0u, m, a, b);
  return a ^ b;
}

__device__ __forceinline__ float gumbel_from_bits(uint32_t bits) {
#pragma clang fp contract(off)
  const float tiny = 1.17549435e-38f;
  float f = __uint_as_float((bits >> 9) | 0x3f800000u) - 1.0f;
  float u = fmaxf(tiny, f + tiny);
  return -xla_log_f32(-xla_log_f32(u));
}

#define AS1 __attribute__((address_space(1)))
#define AS3 __attribute__((address_space(3)))

// ---------------------------------------------------------------------------
// R13 geometry (two 8 KB regions/wave) but a TRUE counted-vmcnt pipeline:
// Q0->A and Q1->B staged up front (16 lines in flight); each phase does
// vmcnt(8) [oldest quarter landed, newer one still in flight] -> consume ->
// lgkmcnt(0) -> restage freed region -> gumbels. vmcnt only reaches 0 for
// the last quarter: the wave always keeps >=8 lines in flight, hiding HBM
// latency under its own consume+gumbel VALU. Tests "R13 failed due to
// drains, not 8 waves/CU". All math + STQ/CONSUMEQ blocks verbatim R13.
// ---------------------------------------------------------------------------
__global__ void __launch_bounds__(256, 2)
dns_kernel(const int* __restrict__ ids, const float* __restrict__ features,
           const int* __restrict__ adj, int* __restrict__ out) {
#pragma clang fp contract(off)
  __shared__ __align__(16) char sbuf[RPB][16384];  // regions A=0, B=8192
  __shared__ __align__(16) float fc[RPB][NF];
  __shared__ __align__(16) float esh[RPB][NK];
  __shared__ int nsh[RPB][NK];
  __shared__ float zb[RPB][NS][4];
  __shared__ int ib[RPB][NS][4];

  const int wave = threadIdx.x >> 6;
  const int k = threadIdx.x & 63;
  const int b = blockIdx.x * RPB + wave;
  char* sb = sbuf[wave];

  float pg[16];
  // gumbel flat index m = ss*NB*NK + b*NK + k  (noise shape (16,16384,64));
  // pure VALU, independent of every load -> fills load latency.
#define GUM1(ss) pg[ss] = gumbel_from_bits(                                  \
      jax_random_bits32((uint32_t)(((ss) * NB + b) * NK + k)))

  const int center = ids[b];
  GUM1(0); GUM1(1);                             // cover ids-load latency

  nsh[wave][k] = adj[(size_t)center * NK + k];
  if (k < NF / 4)
    ((float4*)fc[wave])[k] = ((const float4*)(features + (size_t)center * NF))[k];

  GUM1(2); GUM1(3);                             // cover adj/fc-load latency
  asm volatile("s_waitcnt lgkmcnt(0)" ::: "memory");  // fc/nsh visible in-wave

  // stage pointers (R11/R13-proven): instr slot i stages rows i*8..i*8+7,
  // 8 lanes per 128 B line; swizzle slot es = eg^rg uniform across instrs.
  const int rg = k >> 3;   // row sub-index within a stage instruction
  const int eg = k & 7;    // element slot within the 128 B line
  const int es = eg ^ rg;  // swizzled source slot
  const float4* f4b = (const float4*)features;
#define MKGP(i) const float4* gp##i = f4b + (size_t)nsh[wave][(i) * 8 + rg] * (NF / 4) + es
  MKGP(0); MKGP(1); MKGP(2); MKGP(3); MKGP(4); MKGP(5); MKGP(6); MKGP(7);
#undef MKGP

  // stage quarter q into buffer region h (0 or 8192)  [R13 verbatim]
#define STQ(q, h)                                                            \
  do {                                                                       \
    __builtin_amdgcn_global_load_lds((const AS1 void*)(gp0 + (q) * 8),       \
        (AS3 void*)(sb + (h) + 0 * 1024), 16, 0, 0);                         \
    __builtin_amdgcn_global_load_lds((const AS1 void*)(gp1 + (q) * 8),       \
        (AS3 void*)(sb + (h) + 1 * 1024), 16, 0, 0);                         \
    __builtin_amdgcn_global_load_lds((const AS1 void*)(gp2 + (q) * 8),       \
        (AS3 void*)(sb + (h) + 2 * 1024), 16, 0, 0);                         \
    __builtin_amdgcn_global_load_lds((const AS1 void*)(gp3 + (q) * 8),       \
        (AS3 void*)(sb + (h) + 3 * 1024), 16, 0, 0);                         \
    __builtin_amdgcn_global_load_lds((const AS1 void*)(gp4 + (q) * 8),       \
        (AS3 void*)(sb + (h) + 4 * 1024), 16, 0, 0);                         \
    __builtin_amdgcn_global_load_lds((const AS1 void*)(gp5 + (q) * 8),       \
        (AS3 void*)(sb + (h) + 5 * 1024), 16, 0, 0);                         \
    __builtin_amdgcn_global_load_lds((const AS1 void*)(gp6 + (q) * 8),       \
        (AS3 void*)(sb + (h) + 6 * 1024), 16, 0, 0);                         \
    __builtin_amdgcn_global_load_lds((const AS1 void*)(gp7 + (q) * 8),       \
        (AS3 void*)(sb + (h) + 7 * 1024), 16, 0, 0);                         \
  } while (0)

  // consume quarter q from region h (R8/R13 verbatim): lane k reads its own
  // row, elements in ascending global order j = q*8+j2 -> bit-exact chain.
#define CONSUMEQ(q, h)                                                       \
  do {                                                                       \
    _Pragma("unroll")                                                        \
    for (int j2 = 0; j2 < 8; ++j2) {                                         \
      const float4 v =                                                       \
          *(const float4*)(sb + (h) + k * 128 + ((j2 ^ (k & 7)) << 4));      \
      const int j = (q) * 8 + j2;                                            \
      float d0 = fc[wave][4 * j + 0] - v.x; acc = acc + d0 * d0;             \
      float d1 = fc[wave][4 * j + 1] - v.y; acc = acc + d1 * d1;             \
      float d2 = fc[wave][4 * j + 2] - v.z; acc = acc + d2 * d2;             \
      float d3 = fc[wave][4 * j + 3] - v.w; acc = acc + d3 * d3;             \
    }                                                                        \
  } while (0)

  float acc = 0.0f;

  // --- prologue: fill pipeline with Q0->A and Q1->B (16 lines in flight) ---
  STQ(0, 0);
  STQ(1, 8192);
  GUM1(4); GUM1(5); GUM1(6);

  // --- phase 0: Q0 landed (8 newer still in flight) ---
  asm volatile("s_waitcnt vmcnt(8)" ::: "memory");
  CONSUMEQ(0, 0);
  asm volatile("s_waitcnt lgkmcnt(0)" ::: "memory");  // reads done pre-restage
  STQ(2, 0);                                          // restage A with Q2
  GUM1(7); GUM1(8); GUM1(9);

  // --- phase 1: Q1 landed (Q2 in flight) ---
  asm volatile("s_waitcnt vmcnt(8)" ::: "memory");
  CONSUMEQ(1, 8192);
  asm volatile("s_waitcnt lgkmcnt(0)" ::: "memory");
  STQ(3, 8192);                                       // restage B with Q3
  GUM1(10); GUM1(11); GUM1(12);

  // --- phase 2: Q2 landed (Q3 in flight) ---
  asm volatile("s_waitcnt vmcnt(8)" ::: "memory");
  CONSUMEQ(2, 0);
  GUM1(13); GUM1(14); GUM1(15);

  // --- phase 3: final drain (only mandatory vmcnt(0)) ---
  asm volatile("s_waitcnt vmcnt(0)" ::: "memory");
  CONSUMEQ(3, 8192);
  asm volatile("s_waitcnt lgkmcnt(0)" ::: "memory");

  const float ev = xla_exp_f32(-sqrtf(acc));
  esh[wave][k] = ev;
  asm volatile("s_waitcnt lgkmcnt(0)" ::: "memory");

  // sequential 64-term sum (XLA order): all lanes redundantly via float4
  // broadcast reads; identical ascending order -> bit-exact (R6/R8-verified)
  float s = 0.0f;
  const float4* e4 = (const float4*)esh[wave];
#pragma unroll
  for (int i = 0; i < NK / 4; ++i) {
    float4 v = e4[i];
    s = s + v.x; s = s + v.y; s = s + v.z; s = s + v.w;
  }
  const float logit = xla_log_f32(ev / s);

  // zsh aliases region A (dead: Q2 consumed, no DMA pending after vmcnt(0))
  float (*zsh)[NK + 1] = (float (*)[NK + 1])(void*)sb;
#pragma unroll
  for (int ss = 0; ss < NS; ++ss) {
    zsh[ss][k] = pg[ss] + logit;
  }
  asm volatile("s_waitcnt lgkmcnt(0)" ::: "memory");

  // parallel argmax (R6/R8-verified): lane l owns (samp = l>>2, quarter l&3)
  const int samp = k >> 2;
  const int sub = k & 3;
  const int kbase = sub * 16;
  float best = zsh[samp][kbase];
  int bi = kbase;
#pragma unroll 1
  for (int j = 1; j < 16; ++j) {
    const float v = zsh[samp][kbase + j];
    if (v > best) { best = v; bi = kbase + j; }   // strict > : first index
  }
  zb[wave][samp][sub] = best;
  ib[wave][samp][sub] = bi;
  asm volatile("s_waitcnt lgkmcnt(0)" ::: "memory");

  // combine 4 quarters; ascending q + strict > keeps lowest kk on ties
  if (sub == 0) {
    float bb = zb[wave][samp][0];
    int bbi = ib[wave][samp][0];
#pragma unroll
    for (int qq = 1; qq < 4; ++qq) {
      const float v = zb[wave][samp][qq];
      if (v > bb) { bb = v; bbi = ib[wave][samp][qq]; }
    }
    out[b * NS + samp] = nsh[wave][bbi];
  }
#undef STQ
#undef CONSUMEQ
#undef GUM1
}

extern "C" void kernel_launch(void* const* d_in, const int* in_sizes, int n_in,
                              void* d_out, int out_size, void* d_ws, size_t ws_size,
                              hipStream_t stream) {
  // inputs: ids(int32)[16384], num_samples(1), features(f32)[100000*128],
  //         batch_size(1), adj_info(int32)[100000*64]
  const int* ids = (const int*)d_in[0];
  const float* features = (const float*)d_in[2];
  const int* adj = (const int*)d_in[4];
  int* out = (int*)d_out;
  (void)in_sizes; (void)n_in; (void)out_size; (void)d_ws; (void)ws_size;

  dns_kernel<<<dim3(NB / RPB), dim3(64 * RPB), 0, stream>>>(ids, features, adj, out);
}

// Round 16
// 81.989 us; speedup vs baseline: 1.0893x; 1.0893x over previous
//
#include <hip/hip_runtime.h>
#include <stdint.h>

#define NB 16384      // batch
#define NK 64         // neighbors per node
#define NF 128        // feature dim
#define NS 16         // samples per row
#define RPB 4         // rows (waves) per block

// ---------------------------------------------------------------------------
// Bit-exact replicas of XLA:CPU's float32 exp/log (Cephes-derived polynomials
// from llvm_ir_runtime.cc GenerateVF32Exp/GenerateVF32Log; fmuladd -> FMA).
// DO NOT TOUCH: verified absmax == 0 vs JAX reference in R1/R4/R6-R14.
// ---------------------------------------------------------------------------
__device__ __forceinline__ float xla_exp_f32(float x_in) {
#pragma clang fp contract(off)
  const float exp_hi = 88.3762626647950f;
  const float exp_lo = -88.3762626647949f;
  const float log2ef = 1.44269504088896341f;
  const float c1 = 0.693359375f;
  const float c2 = -2.12194440e-4f;
  const float p0 = 1.9875691500E-4f;
  const float p1 = 1.3981999507E-3f;
  const float p2 = 8.3334519073E-3f;
  const float p3 = 4.1665795894E-2f;
  const float p4 = 1.6666665459E-1f;
  const float p5 = 5.0000001201E-1f;

  float x = fminf(fmaxf(x_in, exp_lo), exp_hi);
  float fx = floorf(fmaf(x, log2ef, 0.5f));
  float tmp = c1 * fx;
  float z2 = c2 * fx;
  x = x - tmp;
  x = x - z2;
  float z = x * x;
  float y = fmaf(x, p0, p1);
  y = fmaf(y, x, p2);
  y = fmaf(y, x, p3);
  y = fmaf(y, x, p4);
  y = fmaf(y, x, p5);
  y = fmaf(y, z, x);
  y = y + 1.0f;
  int n = (int)fx;
  float two_n = __int_as_float((n + 127) << 23);
  return fmaxf(y * two_n, x_in);
}

__device__ __forceinline__ float xla_log_f32(float x_in) {
#pragma clang fp contract(off)
  const float sqrthf = 0.707106781186547524f;
  const float p0 = 7.0376836292E-2f;
  const float p1 = -1.1514610310E-1f;
  const float p2 = 1.1676998740E-1f;
  const float p3 = -1.2420140846E-1f;
  const float p4 = 1.4249322787E-1f;
  const float p5 = -1.6668057665E-1f;
  const float p6 = 2.0000714765E-1f;
  const float p7 = -2.4999993993E-1f;
  const float p8 = 3.3333331174E-1f;
  const float q1 = -2.12194440e-4f;
  const float q2 = 0.693359375f;

  float t = fmaxf(x_in, __uint_as_float(0x00800000u));
  uint32_t bits = __float_as_uint(t);
  float e = (float)((int)(bits >> 23) - 0x7f) + 1.0f;
  float m = __uint_as_float((bits & 0x007fffffu) | 0x3f000000u);
  bool lt = (m < sqrthf);
  float madd = lt ? m : 0.0f;
  e = e - (lt ? 1.0f : 0.0f);
  m = (m + madd) - 1.0f;

  float z = m * m;
  float y = fmaf(m, p0, p1);
  y = fmaf(y, m, p2);
  y = fmaf(y, m, p3);
  y = fmaf(y, m, p4);
  y = fmaf(y, m, p5);
  y = fmaf(y, m, p6);
  y = fmaf(y, m, p7);
  y = fmaf(y, m, p8);
  y = y * m;
  y = y * z;
  y = fmaf(e, q1, y);
  y = y - 0.5f * z;
  float r = m + y;
  r = fmaf(e, q2, r);
  return r;
}

// ---------------------------------------------------------------------------
// Threefry-2x32 with key (0, 42) == jax.random.key(42).
// ---------------------------------------------------------------------------
__device__ __forceinline__ void threefry2x32_k42(uint32_t c0, uint32_t c1,
                                                 uint32_t& o0, uint32_t& o1) {
  const uint32_t k0 = 0u, k1 = 42u;
  const uint32_t k2 = k0 ^ k1 ^ 0x1BD11BDAu;
  uint32_t x0 = c0 + k0, x1 = c1 + k1;
#define TF_R(r) { x0 += x1; x1 = (x1 << (r)) | (x1 >> (32 - (r))); x1 ^= x0; }
  TF_R(13) TF_R(15) TF_R(26) TF_R(6)
  x0 += k1; x1 += k2 + 1u;
  TF_R(17) TF_R(29) TF_R(16) TF_R(24)
  x0 += k2; x1 += k0 + 2u;
  TF_R(13) TF_R(15) TF_R(26) TF_R(6)
  x0 += k0; x1 += k1 + 3u;
  TF_R(17) TF_R(29) TF_R(16) TF_R(24)
  x0 += k1; x1 += k2 + 4u;
  TF_R(13) TF_R(15) TF_R(26) TF_R(6)
  x0 += k2; x1 += k0 + 5u;
#undef TF_R
  o0 = x0; o1 = x1;
}

// jax partitionable threefry, 32-bit path: bits[m] = out0 ^ out1, m < 2^24.
__device__ __forceinline__ uint32_t jax_random_bits32(uint32_t m) {
  uint32_t a, b;
  threefry2x32_k42(0u, m, a, b);
  return a ^ b;
}

__device__ __forceinline__ float gumbel_from_bits(uint32_t bits) {
#pragma clang fp contract(off)
  const float tiny = 1.17549435e-38f;
  float f = __uint_as_float((bits >> 9) | 0x3f800000u) - 1.0f;
  float u = fmaxf(tiny, f + tiny);
  return -xla_log_f32(-xla_log_f32(u));
}

#define AS1 __attribute__((address_space(1)))
#define AS3 __attribute__((address_space(3)))

// ---------------------------------------------------------------------------
// R11 VERBATIM (session best: 81.6 us). Full-line coalesced staging via
// global_load_lds (8 lanes/128 B line, source-side XOR swizzle), stage
// pointers computed once + bumped per quarter, gumbel VALU work covering
// the ids/adj prologue latency and all four vmcnt(0) drain shadows.
// All math blocks bit-exact vs JAX reference (absmax 0).
// ---------------------------------------------------------------------------
__global__ void __launch_bounds__(256)
dns_kernel(const int* __restrict__ ids, const float* __restrict__ features,
           const int* __restrict__ adj, int* __restrict__ out) {
#pragma clang fp contract(off)
  __shared__ __align__(16) char sbuf[RPB][8192];   // stage buf, later zsh
  __shared__ __align__(16) float fc[RPB][NF];
  __shared__ __align__(16) float esh[RPB][NK];
  __shared__ int nsh[RPB][NK];
  __shared__ float zb[RPB][NS][4];
  __shared__ int ib[RPB][NS][4];

  const int wave = threadIdx.x >> 6;
  const int k = threadIdx.x & 63;
  const int b = blockIdx.x * RPB + wave;
  char* sb = sbuf[wave];

  float pg[16];
  // gumbel flat index m = ss*NB*NK + b*NK + k  (noise shape (16,16384,64));
  // pure VALU, independent of every load -> scheduler fills load latency.
#define GUM1(ss) pg[ss] = gumbel_from_bits(                                  \
      jax_random_bits32((uint32_t)(((ss) * NB + b) * NK + k)))

  const int center = ids[b];
  GUM1(0); GUM1(1); GUM1(2);                    // cover ids-load latency

  if (k < NF / 4)
    ((float4*)fc[wave])[k] = ((const float4*)(features + (size_t)center * NF))[k];
  nsh[wave][k] = adj[(size_t)center * NK + k];

  GUM1(3); GUM1(4); GUM1(5);                    // cover adj/fc-load latency
  asm volatile("s_waitcnt lgkmcnt(0)" ::: "memory");  // fc/nsh visible in-wave

  const int rg = k >> 3;   // row sub-index within a stage instruction
  const int eg = k & 7;    // element slot within the 128 B quarter
  const int es = eg ^ rg;  // swizzled source slot (uniform across instrs)

  // stage base pointers, one per stage-instruction slot (computed once)
  const float4* f4b = (const float4*)features;
#define MKGP(i) const float4* gp##i = f4b + (size_t)nsh[wave][(i) * 8 + rg] * (NF / 4) + es
  MKGP(0); MKGP(1); MKGP(2); MKGP(3); MKGP(4); MKGP(5); MKGP(6); MKGP(7);
#undef MKGP

  // STAGE one quarter: 8 instrs, each stages rows i*8..i*8+7 (one full 128 B
  // line per row, 8 lanes per line); then bump pointers to the next quarter.
#define STAGEQ()                                                             \
  do {                                                                       \
    __builtin_amdgcn_global_load_lds((const AS1 void*)gp0,                   \
        (AS3 void*)(sb + 0 * 1024), 16, 0, 0);                               \
    __builtin_amdgcn_global_load_lds((const AS1 void*)gp1,                   \
        (AS3 void*)(sb + 1 * 1024), 16, 0, 0);                               \
    __builtin_amdgcn_global_load_lds((const AS1 void*)gp2,                   \
        (AS3 void*)(sb + 2 * 1024), 16, 0, 0);                               \
    __builtin_amdgcn_global_load_lds((const AS1 void*)gp3,                   \
        (AS3 void*)(sb + 3 * 1024), 16, 0, 0);                               \
    __builtin_amdgcn_global_load_lds((const AS1 void*)gp4,                   \
        (AS3 void*)(sb + 4 * 1024), 16, 0, 0);                               \
    __builtin_amdgcn_global_load_lds((const AS1 void*)gp5,                   \
        (AS3 void*)(sb + 5 * 1024), 16, 0, 0);                               \
    __builtin_amdgcn_global_load_lds((const AS1 void*)gp6,                   \
        (AS3 void*)(sb + 6 * 1024), 16, 0, 0);                               \
    __builtin_amdgcn_global_load_lds((const AS1 void*)gp7,                   \
        (AS3 void*)(sb + 7 * 1024), 16, 0, 0);                               \
    gp0 += 8; gp1 += 8; gp2 += 8; gp3 += 8;                                  \
    gp4 += 8; gp5 += 8; gp6 += 8; gp7 += 8;                                  \
  } while (0)

  // consume quarter q (R8/R10 verbatim): lane k reads its own row, elements
  // in ascending global order j = q*8+j2 -> bit-exact sequential chain.
#define CONSUMEQ(q)                                                          \
  do {                                                                       \
    _Pragma("unroll")                                                        \
    for (int j2 = 0; j2 < 8; ++j2) {                                         \
      const float4 v =                                                       \
          *(const float4*)(sb + k * 128 + ((j2 ^ (k & 7)) << 4));            \
      const int j = (q) * 8 + j2;                                            \
      float d0 = fc[wave][4 * j + 0] - v.x; acc = acc + d0 * d0;             \
      float d1 = fc[wave][4 * j + 1] - v.y; acc = acc + d1 * d1;             \
      float d2 = fc[wave][4 * j + 2] - v.z; acc = acc + d2 * d2;             \
      float d3 = fc[wave][4 * j + 3] - v.w; acc = acc + d3 * d3;             \
    }                                                                        \
  } while (0)

  float acc = 0.0f;

  STAGEQ(); GUM1(6); GUM1(7); GUM1(8);
  asm volatile("s_waitcnt vmcnt(0)" ::: "memory");
  CONSUMEQ(0);
  asm volatile("s_waitcnt lgkmcnt(0)" ::: "memory");

  STAGEQ(); GUM1(9); GUM1(10); GUM1(11);
  asm volatile("s_waitcnt vmcnt(0)" ::: "memory");
  CONSUMEQ(1);
  asm volatile("s_waitcnt lgkmcnt(0)" ::: "memory");

  STAGEQ(); GUM1(12); GUM1(13);
  asm volatile("s_waitcnt vmcnt(0)" ::: "memory");
  CONSUMEQ(2);
  asm volatile("s_waitcnt lgkmcnt(0)" ::: "memory");

  STAGEQ(); GUM1(14); GUM1(15);
  asm volatile("s_waitcnt vmcnt(0)" ::: "memory");
  CONSUMEQ(3);
  asm volatile("s_waitcnt lgkmcnt(0)" ::: "memory");

  const float ev = xla_exp_f32(-sqrtf(acc));
  esh[wave][k] = ev;
  asm volatile("s_waitcnt lgkmcnt(0)" ::: "memory");

  // sequential 64-term sum (XLA order): all lanes redundantly via float4
  // broadcast reads; identical ascending order -> bit-exact (R6/R8-verified)
  float s = 0.0f;
  const float4* e4 = (const float4*)esh[wave];
#pragma unroll
  for (int i = 0; i < NK / 4; ++i) {
    float4 v = e4[i];
    s = s + v.x; s = s + v.y; s = s + v.z; s = s + v.w;
  }
  const float logit = xla_log_f32(ev / s);

  // zsh aliases the (dead) stage buffer: 16 x 65 floats = 4160 B < 8192 B
  float (*zsh)[NK + 1] = (float (*)[NK + 1])(void*)sb;
#pragma unroll
  for (int ss = 0; ss < NS; ++ss) {
    zsh[ss][k] = pg[ss] + logit;
  }
  asm volatile("s_waitcnt lgkmcnt(0)" ::: "memory");

  // parallel argmax (R6/R8-verified): lane l owns (samp = l>>2, quarter l&3)
  const int samp = k >> 2;
  const int sub = k & 3;
  const int kbase = sub * 16;
  float best = zsh[samp][kbase];
  int bi = kbase;
#pragma unroll 1
  for (int j = 1; j < 16; ++j) {
    const float v = zsh[samp][kbase + j];
    if (v > best) { best = v; bi = kbase + j; }   // strict > : first index
  }
  zb[wave][samp][sub] = best;
  ib[wave][samp][sub] = bi;
  asm volatile("s_waitcnt lgkmcnt(0)" ::: "memory");

  // combine 4 quarters; ascending q + strict > keeps lowest kk on ties
  if (sub == 0) {
    float bb = zb[wave][samp][0];
    int bbi = ib[wave][samp][0];
#pragma unroll
    for (int qq = 1; qq < 4; ++qq) {
      const float v = zb[wave][samp][qq];
      if (v > bb) { bb = v; bbi = ib[wave][samp][qq]; }
    }
    out[b * NS + samp] = nsh[wave][bbi];
  }
#undef STAGEQ
#undef CONSUMEQ
#undef GUM1
}

extern "C" void kernel_launch(void* const* d_in, const int* in_sizes, int n_in,
                              void* d_out, int out_size, void* d_ws, size_t ws_size,
                              hipStream_t stream) {
  // inputs: ids(int32)[16384], num_samples(1), features(f32)[100000*128],
  //         batch_size(1), adj_info(int32)[100000*64]
  const int* ids = (const int*)d_in[0];
  const float* features = (const float*)d_in[2];
  const int* adj = (const int*)d_in[4];
  int* out = (int*)d_out;
  (void)in_sizes; (void)n_in; (void)out_size; (void)d_ws; (void)ws_size;

  dns_kernel<<<dim3(NB / RPB), dim3(64 * RPB), 0, stream>>>(ids, features, adj, out);
}